// Round 1
// baseline (633.749 us; speedup 1.0000x reference)
//
#include <hip/hip_runtime.h>
#include <hip/hip_bf16.h>

using f4 = __attribute__((ext_vector_type(4))) float;

#define N_NODES_DIM 128   // D_IN
#define YCOLS 512         // q|k|v|skip concatenated

// ---------------------------------------------------------------------------
// Kernel 1: fused GEMM  y[n, 0:512] = x[n, :] @ [Wq|Wk|Wv|Wskip] + bias
// 64x64 tile per block, 256 threads, K=128 staged in LDS.
// ---------------------------------------------------------------------------
__global__ __launch_bounds__(256) void qkvs_gemm(
    const float* __restrict__ x,
    const float* __restrict__ Wq, const float* __restrict__ bq,
    const float* __restrict__ Wk, const float* __restrict__ bk,
    const float* __restrict__ Wv, const float* __restrict__ bv,
    const float* __restrict__ Ws, const float* __restrict__ bs,
    float* __restrict__ y, int n)
{
    __shared__ float xs[64][128];   // XOR-swizzled along k to kill bank conflicts
    __shared__ float wt[128][64];

    const int cb   = blockIdx.x;        // 0..7 -> which 64-col slice of 512
    const int rb   = blockIdx.y;
    const int row0 = rb * 64;
    const int which = cb >> 1;          // 0=q 1=k 2=v 3=skip
    const int col0  = (cb & 1) * 64;    // column offset inside that W

    const float* W = (which == 0) ? Wq : (which == 1) ? Wk : (which == 2) ? Wv : Ws;
    const float* b = (which == 0) ? bq : (which == 1) ? bk : (which == 2) ? bv : bs;

    const int t = threadIdx.x;

    // load x tile (64 rows x 128 k), swizzled store: col c -> c ^ ((r&7)<<2)
    #pragma unroll
    for (int i = 0; i < 32; ++i) {
        int l = t + i * 256;
        int r = l >> 7, c = l & 127;
        int gr = row0 + r;
        float v = (gr < n) ? x[(size_t)gr * 128 + c] : 0.f;
        xs[r][c ^ ((r & 7) << 2)] = v;
    }
    // load W tile (128 k x 64 cols)
    #pragma unroll
    for (int i = 0; i < 32; ++i) {
        int l = t + i * 256;
        int k = l >> 6, c = l & 63;
        wt[k][c] = W[(size_t)k * 128 + col0 + c];
    }
    __syncthreads();

    const int tx = t & 15, ty = t >> 4;
    const int r0 = ty * 4, c0 = tx * 4;

    f4 acc[4];
    #pragma unroll
    for (int i = 0; i < 4; ++i) acc[i] = (f4)(0.f);

    #pragma unroll 4
    for (int k = 0; k < 128; k += 4) {
        f4 a_[4], w_[4];
        #pragma unroll
        for (int i = 0; i < 4; ++i) {
            int rr = r0 + i;
            a_[i] = *reinterpret_cast<const f4*>(&xs[rr][k ^ ((rr & 7) << 2)]);
        }
        #pragma unroll
        for (int j = 0; j < 4; ++j)
            w_[j] = *reinterpret_cast<const f4*>(&wt[k + j][c0]);
        #pragma unroll
        for (int i = 0; i < 4; ++i) {
            #pragma unroll
            for (int kk = 0; kk < 4; ++kk)
                acc[i] += a_[i][kk] * w_[kk];
        }
    }

    const f4 bb = *reinterpret_cast<const f4*>(&b[col0 + c0]);
    #pragma unroll
    for (int i = 0; i < 4; ++i) {
        int gr = row0 + r0 + i;
        if (gr < n) {
            *reinterpret_cast<f4*>(&y[(size_t)gr * YCOLS + which * 128 + col0 + c0]) =
                acc[i] + bb;
        }
    }
}

// ---------------------------------------------------------------------------
// Kernel 2: per-edge pass. One 64-lane wave per edge.
// alpha = (q[dst] . k[src]) / 8 per head; a = exp(alpha) (no max needed:
// |alpha| <~ 8 so fp32 exp is safe and the softmax ratio is identical).
// Scatter a * v[src] into agg (=d_out) and a into denom via atomics.
// ---------------------------------------------------------------------------
__global__ __launch_bounds__(256) void edge_kernel(
    const int* __restrict__ ei, const float* __restrict__ y,
    float* __restrict__ agg, float* __restrict__ denom, int E_)
{
    const int e    = blockIdx.x * 4 + (threadIdx.x >> 6);
    const int lane = threadIdx.x & 63;
    if (e >= E_) return;

    const int src = ei[e];
    const int dst = ei[E_ + e];

    const float* qb = y + (size_t)dst * YCOLS;          // q cols 0..127
    const float* kb = y + (size_t)src * YCOLS + 128;    // k
    const float* vb = y + (size_t)src * YCOLS + 256;    // v

    float q0 = qb[lane], q1 = qb[64 + lane];
    float k0 = kb[lane], k1 = kb[64 + lane];
    float p0 = q0 * k0;
    float p1 = q1 * k1;
    #pragma unroll
    for (int off = 32; off > 0; off >>= 1) {
        p0 += __shfl_xor(p0, off, 64);
        p1 += __shfl_xor(p1, off, 64);
    }
    const float a0 = __expf(p0 * 0.125f);
    const float a1 = __expf(p1 * 0.125f);

    atomicAdd(&agg[(size_t)dst * 128 + lane],      a0 * vb[lane]);
    atomicAdd(&agg[(size_t)dst * 128 + 64 + lane], a1 * vb[64 + lane]);
    if (lane == 0)  atomicAdd(&denom[dst * 2 + 0], a0);
    if (lane == 32) atomicAdd(&denom[dst * 2 + 1], a1);
}

// ---------------------------------------------------------------------------
// Kernel 3: out = agg / max(denom,1e-16) + skip
// ---------------------------------------------------------------------------
__global__ __launch_bounds__(256) void finalize_kernel(
    const float* __restrict__ y, const float* __restrict__ denom,
    float* __restrict__ out, int n)
{
    const int i = blockIdx.x * blockDim.x + threadIdx.x;
    if (i >= n * 128) return;
    const int node = i >> 7;
    const int j    = i & 127;
    const int h    = j >> 6;
    const float d  = denom[node * 2 + h];
    const float a  = out[i];
    out[i] = a / fmaxf(d, 1e-16f) + y[(size_t)node * YCOLS + 384 + j];
}

extern "C" void kernel_launch(void* const* d_in, const int* in_sizes, int n_in,
                              void* d_out, int out_size, void* d_ws, size_t ws_size,
                              hipStream_t stream) {
    const float* x    = (const float*)d_in[0];
    const int*   ei   = (const int*)d_in[1];
    const float* Wq   = (const float*)d_in[2];
    const float* bq   = (const float*)d_in[3];
    const float* Wk   = (const float*)d_in[4];
    const float* bk   = (const float*)d_in[5];
    const float* Wv   = (const float*)d_in[6];
    const float* bv   = (const float*)d_in[7];
    const float* Ws   = (const float*)d_in[8];
    const float* bs   = (const float*)d_in[9];

    const int N = in_sizes[0] / 128;
    const int E = in_sizes[1] / 2;

    float* y     = (float*)d_ws;                 // [N][512]
    float* denom = y + (size_t)N * YCOLS;        // [N][2]
    float* out   = (float*)d_out;                // agg accumulates here

    hipMemsetAsync(out,   0, (size_t)N * 128 * sizeof(float), stream);
    hipMemsetAsync(denom, 0, (size_t)N * 2   * sizeof(float), stream);

    dim3 ggrid(8, (N + 63) / 64);
    qkvs_gemm<<<ggrid, 256, 0, stream>>>(x, Wq, bq, Wk, bk, Wv, bv, Ws, bs, y, N);

    edge_kernel<<<(E + 3) / 4, 256, 0, stream>>>(ei, y, out, denom, E);

    finalize_kernel<<<((size_t)N * 128 + 255) / 256, 256, 0, stream>>>(y, denom, out, N);
}

// Round 2
// 416.137 us; speedup vs baseline: 1.5229x; 1.5229x over previous
//
#include <hip/hip_runtime.h>
#include <hip/hip_bf16.h>

using f4 = __attribute__((ext_vector_type(4))) float;

#define YCOLS 512         // q|k|v|skip concatenated

// ---------------------------------------------------------------------------
// Kernel 1: fused GEMM  y[n, 0:512] = x[n, :] @ [Wq|Wk|Wv|Wskip] + bias
// (unchanged from round 1)
// ---------------------------------------------------------------------------
__global__ __launch_bounds__(256) void qkvs_gemm(
    const float* __restrict__ x,
    const float* __restrict__ Wq, const float* __restrict__ bq,
    const float* __restrict__ Wk, const float* __restrict__ bk,
    const float* __restrict__ Wv, const float* __restrict__ bv,
    const float* __restrict__ Ws, const float* __restrict__ bs,
    float* __restrict__ y, int n)
{
    __shared__ float xs[64][128];
    __shared__ float wt[128][64];

    const int cb   = blockIdx.x;
    const int rb   = blockIdx.y;
    const int row0 = rb * 64;
    const int which = cb >> 1;
    const int col0  = (cb & 1) * 64;

    const float* W = (which == 0) ? Wq : (which == 1) ? Wk : (which == 2) ? Wv : Ws;
    const float* b = (which == 0) ? bq : (which == 1) ? bk : (which == 2) ? bv : bs;

    const int t = threadIdx.x;

    #pragma unroll
    for (int i = 0; i < 32; ++i) {
        int l = t + i * 256;
        int r = l >> 7, c = l & 127;
        int gr = row0 + r;
        float v = (gr < n) ? x[(size_t)gr * 128 + c] : 0.f;
        xs[r][c ^ ((r & 7) << 2)] = v;
    }
    #pragma unroll
    for (int i = 0; i < 32; ++i) {
        int l = t + i * 256;
        int k = l >> 6, c = l & 63;
        wt[k][c] = W[(size_t)k * 128 + col0 + c];
    }
    __syncthreads();

    const int tx = t & 15, ty = t >> 4;
    const int r0 = ty * 4, c0 = tx * 4;

    f4 acc[4];
    #pragma unroll
    for (int i = 0; i < 4; ++i) acc[i] = (f4)(0.f);

    #pragma unroll 4
    for (int k = 0; k < 128; k += 4) {
        f4 a_[4], w_[4];
        #pragma unroll
        for (int i = 0; i < 4; ++i) {
            int rr = r0 + i;
            a_[i] = *reinterpret_cast<const f4*>(&xs[rr][k ^ ((rr & 7) << 2)]);
        }
        #pragma unroll
        for (int j = 0; j < 4; ++j)
            w_[j] = *reinterpret_cast<const f4*>(&wt[k + j][c0]);
        #pragma unroll
        for (int i = 0; i < 4; ++i) {
            #pragma unroll
            for (int kk = 0; kk < 4; ++kk)
                acc[i] += a_[i][kk] * w_[kk];
        }
    }

    const f4 bb = *reinterpret_cast<const f4*>(&b[col0 + c0]);
    #pragma unroll
    for (int i = 0; i < 4; ++i) {
        int gr = row0 + r0 + i;
        if (gr < n) {
            *reinterpret_cast<f4*>(&y[(size_t)gr * YCOLS + which * 128 + col0 + c0]) =
                acc[i] + bb;
        }
    }
}

// ---------------------------------------------------------------------------
// Counting-sort phase: histogram -> per-wave scan + 1 atomic/wave -> scatter
// ---------------------------------------------------------------------------
__global__ __launch_bounds__(256) void hist_kernel(
    const int* __restrict__ ei, int* __restrict__ count, int E_)
{
    int e = blockIdx.x * 256 + threadIdx.x;
    if (e < E_) atomicAdd(&count[ei[E_ + e]], 1);
}

__global__ __launch_bounds__(256) void bucket_assign(
    const int* __restrict__ count, int* __restrict__ offs,
    int* __restrict__ cursor, int* __restrict__ gcount, int n)
{
    int i = blockIdx.x * 256 + threadIdx.x;
    int lane = threadIdx.x & 63;
    int c = (i < n) ? count[i] : 0;
    int v = c;
    #pragma unroll
    for (int off = 1; off < 64; off <<= 1) {
        int t = __shfl_up(v, off, 64);
        if (lane >= off) v += t;
    }
    int excl  = v - c;                 // exclusive prefix within wave
    int total = __shfl(v, 63, 64);     // wave total
    int base = 0;
    if (lane == 63) base = atomicAdd(gcount, total);
    base = __shfl(base, 63, 64);
    if (i < n) { offs[i] = base + excl; cursor[i] = base + excl; }
}

__global__ __launch_bounds__(256) void scatter_kernel(
    const int* __restrict__ ei, int* __restrict__ cursor,
    int* __restrict__ sorted_src, int E_)
{
    int e = blockIdx.x * 256 + threadIdx.x;
    if (e >= E_) return;
    int src = ei[e];
    int dst = ei[E_ + e];
    int pos = atomicAdd(&cursor[dst], 1);
    sorted_src[pos] = src;
}

// ---------------------------------------------------------------------------
// Kernel 4: one wave per dst node. q read once; serial loop over incoming
// edges (unrolled x2 for ILP); register accumulation; fused finalize + skip;
// single non-atomic coalesced write of the output row.
// ---------------------------------------------------------------------------
__global__ __launch_bounds__(256) void node_agg(
    const float* __restrict__ y, const int* __restrict__ offs,
    const int* __restrict__ count, const int* __restrict__ sorted_src,
    float* __restrict__ out, int n)
{
    const int node = blockIdx.x * 4 + (threadIdx.x >> 6);
    const int lane = threadIdx.x & 63;
    if (node >= n) return;

    const float* yn = y + (size_t)node * YCOLS;
    const float q0 = yn[lane], q1 = yn[64 + lane];
    const int deg  = count[node];
    const int base = offs[node];

    float acc0 = 0.f, acc1 = 0.f, den0 = 0.f, den1 = 0.f;

    int e = 0;
    for (; e + 2 <= deg; e += 2) {
        const int sA = sorted_src[base + e];
        const int sB = sorted_src[base + e + 1];
        const float* ka = y + (size_t)sA * YCOLS + 128;
        const float* kb = y + (size_t)sB * YCOLS + 128;
        float ka0 = ka[lane], ka1 = ka[64 + lane], va0 = ka[128 + lane], va1 = ka[192 + lane];
        float kb0 = kb[lane], kb1 = kb[64 + lane], vb0 = kb[128 + lane], vb1 = kb[192 + lane];
        float pa0 = q0 * ka0, pa1 = q1 * ka1;
        float pb0 = q0 * kb0, pb1 = q1 * kb1;
        #pragma unroll
        for (int off = 32; off > 0; off >>= 1) {
            pa0 += __shfl_xor(pa0, off, 64);
            pa1 += __shfl_xor(pa1, off, 64);
            pb0 += __shfl_xor(pb0, off, 64);
            pb1 += __shfl_xor(pb1, off, 64);
        }
        float aa0 = __expf(pa0 * 0.125f), aa1 = __expf(pa1 * 0.125f);
        float ab0 = __expf(pb0 * 0.125f), ab1 = __expf(pb1 * 0.125f);
        den0 += aa0 + ab0;  den1 += aa1 + ab1;
        acc0 += aa0 * va0 + ab0 * vb0;
        acc1 += aa1 * va1 + ab1 * vb1;
    }
    if (e < deg) {
        const int sA = sorted_src[base + e];
        const float* ka = y + (size_t)sA * YCOLS + 128;
        float k0 = ka[lane], k1 = ka[64 + lane], v0 = ka[128 + lane], v1 = ka[192 + lane];
        float p0 = q0 * k0, p1 = q1 * k1;
        #pragma unroll
        for (int off = 32; off > 0; off >>= 1) {
            p0 += __shfl_xor(p0, off, 64);
            p1 += __shfl_xor(p1, off, 64);
        }
        float a0 = __expf(p0 * 0.125f), a1 = __expf(p1 * 0.125f);
        den0 += a0;  den1 += a1;
        acc0 += a0 * v0;  acc1 += a1 * v1;
    }

    out[(size_t)node * 128 + lane]      = acc0 / fmaxf(den0, 1e-16f) + yn[384 + lane];
    out[(size_t)node * 128 + 64 + lane] = acc1 / fmaxf(den1, 1e-16f) + yn[448 + lane];
}

extern "C" void kernel_launch(void* const* d_in, const int* in_sizes, int n_in,
                              void* d_out, int out_size, void* d_ws, size_t ws_size,
                              hipStream_t stream) {
    const float* x    = (const float*)d_in[0];
    const int*   ei   = (const int*)d_in[1];
    const float* Wq   = (const float*)d_in[2];
    const float* bq   = (const float*)d_in[3];
    const float* Wk   = (const float*)d_in[4];
    const float* bk   = (const float*)d_in[5];
    const float* Wv   = (const float*)d_in[6];
    const float* bv   = (const float*)d_in[7];
    const float* Ws   = (const float*)d_in[8];
    const float* bs   = (const float*)d_in[9];

    const int N = in_sizes[0] / 128;
    const int E = in_sizes[1] / 2;

    float* y          = (float*)d_ws;                    // [N][512]
    int*   count      = (int*)(y + (size_t)N * YCOLS);   // [N]
    int*   offs       = count + N;                       // [N]
    int*   cursor     = offs + N;                        // [N]
    int*   gcount     = cursor + N;                      // [1]
    int*   sorted_src = gcount + 1;                      // [E]
    float* out        = (float*)d_out;

    hipMemsetAsync(count,  0, (size_t)N * sizeof(int), stream);
    hipMemsetAsync(gcount, 0, sizeof(int), stream);

    dim3 ggrid(8, (N + 63) / 64);
    qkvs_gemm<<<ggrid, 256, 0, stream>>>(x, Wq, bq, Wk, bk, Wv, bv, Ws, bs, y, N);

    hist_kernel<<<(E + 255) / 256, 256, 0, stream>>>(ei, count, E);
    bucket_assign<<<(N + 255) / 256, 256, 0, stream>>>(count, offs, cursor, gcount, N);
    scatter_kernel<<<(E + 255) / 256, 256, 0, stream>>>(ei, cursor, sorted_src, E);

    node_agg<<<(N + 3) / 4, 256, 0, stream>>>(y, offs, count, sorted_src, out, N);
}

// Round 3
// 233.610 us; speedup vs baseline: 2.7129x; 1.7813x over previous
//
#include <hip/hip_runtime.h>
#include <hip/hip_bf16.h>

typedef __attribute__((ext_vector_type(4))) float f32x4;
typedef __attribute__((ext_vector_type(8))) short bf16x8;   // 8 bf16 in 4 VGPRs

#define AS1 __attribute__((address_space(1)))
#define AS3 __attribute__((address_space(3)))

static __device__ __forceinline__ ushort f2bf(float v) {
    __hip_bfloat16 h = __float2bfloat16(v);
    return *reinterpret_cast<ushort*>(&h);
}

// ---------------------------------------------------------------------------
// convert x (fp32) -> xb (bf16), 8 elems/thread
// ---------------------------------------------------------------------------
__global__ __launch_bounds__(256) void conv_x(
    const float* __restrict__ x, ushort* __restrict__ xb, long total)
{
    long id = (long)blockIdx.x * 256 + threadIdx.x;
    long base = id * 8;
    if (base >= total) return;
    f32x4 a = *reinterpret_cast<const f32x4*>(x + base);
    f32x4 b = *reinterpret_cast<const f32x4*>(x + base + 4);
    uint4 o;
    o.x = (uint)f2bf(a[0]) | ((uint)f2bf(a[1]) << 16);
    o.y = (uint)f2bf(a[2]) | ((uint)f2bf(a[3]) << 16);
    o.z = (uint)f2bf(b[0]) | ((uint)f2bf(b[1]) << 16);
    o.w = (uint)f2bf(b[2]) | ((uint)f2bf(b[3]) << 16);
    *reinterpret_cast<uint4*>(xb + base) = o;
}

// ---------------------------------------------------------------------------
// build WcatT[col 0..511][k 0..127] bf16 (transposed, col-major for B staging)
// and bcat[512] fp32
// ---------------------------------------------------------------------------
__global__ __launch_bounds__(256) void conv_w(
    const float* __restrict__ Wq, const float* __restrict__ bq,
    const float* __restrict__ Wk, const float* __restrict__ bk,
    const float* __restrict__ Wv, const float* __restrict__ bv,
    const float* __restrict__ Ws, const float* __restrict__ bs,
    ushort* __restrict__ WcatT, float* __restrict__ bcat)
{
    int id = blockIdx.x * 256 + threadIdx.x;   // grid 256 -> 65536 threads
    int col = id >> 7, k = id & 127;
    int which = col >> 7, c = col & 127;
    const float* W = (which == 0) ? Wq : (which == 1) ? Wk : (which == 2) ? Wv : Ws;
    WcatT[(size_t)col * 128 + k] = f2bf(W[(size_t)k * 128 + c]);
    if (id < 512) {
        int wh = id >> 7;
        const float* b = (wh == 0) ? bq : (wh == 1) ? bk : (wh == 2) ? bv : bs;
        bcat[id] = b[id & 127];
    }
}

// ---------------------------------------------------------------------------
// MFMA GEMM: yb[n][512] = bf16( xb[n][128] @ WcatT^T + bcat )
// 128x128 tile, 4 waves x (64x64), full K=128 in LDS, swizzled staging.
// ---------------------------------------------------------------------------
__global__ __launch_bounds__(256) void qkvs_mfma(
    const ushort* __restrict__ xb, const ushort* __restrict__ WcatT,
    const float* __restrict__ bcat, ushort* __restrict__ yb, int n)
{
    __shared__ ushort smA[128 * 128];   // 32 KB, [row][128 k] chunk-swizzled
    __shared__ ushort smB[128 * 128];   // 32 KB, [col][128 k] chunk-swizzled

    const int t    = threadIdx.x;
    const int lane = t & 63;
    const int w    = t >> 6;
    const int wm   = w >> 1, wn = w & 1;
    const int row0 = blockIdx.y * 128;
    const int col0 = blockIdx.x * 128;

    // stage A and B: 2048 chunks of 16B each; pre-swizzled global source so
    // linear global_load_lds dest lands chunk^(row&7)-swizzled (m173 pattern)
    #pragma unroll
    for (int i = 0; i < 8; ++i) {
        int L = i * 256 + t;
        int r = L >> 4, ck = L & 15;
        int gr = min(row0 + r, n - 1);
        const ushort* gpA = xb + (size_t)gr * 128 + ((ck ^ (r & 7)) << 3);
        __builtin_amdgcn_global_load_lds((const AS1 void*)gpA,
            (AS3 void*)(smA + (size_t)(i * 256 + (t & 192)) * 8), 16, 0, 0);
        const ushort* gpB = WcatT + (size_t)(col0 + r) * 128 + ((ck ^ (r & 7)) << 3);
        __builtin_amdgcn_global_load_lds((const AS1 void*)gpB,
            (AS3 void*)(smB + (size_t)(i * 256 + (t & 192)) * 8), 16, 0, 0);
    }
    __syncthreads();

    f32x4 acc[4][4];
    #pragma unroll
    for (int i = 0; i < 4; ++i)
        #pragma unroll
        for (int j = 0; j < 4; ++j) acc[i][j] = (f32x4)(0.f);

    #pragma unroll
    for (int kb = 0; kb < 128; kb += 32) {
        const int kc = kb >> 3;          // chunk base: 0,4,8,12
        bf16x8 a[4], b[4];
        #pragma unroll
        for (int rm = 0; rm < 4; ++rm) {
            int r  = wm * 64 + rm * 16 + (lane & 15);
            int ck = (kc + (lane >> 4)) ^ (r & 7);
            a[rm] = *reinterpret_cast<const bf16x8*>(smA + (size_t)r * 128 + ck * 8);
        }
        #pragma unroll
        for (int cn = 0; cn < 4; ++cn) {
            int r  = wn * 64 + cn * 16 + (lane & 15);
            int ck = (kc + (lane >> 4)) ^ (r & 7);
            b[cn] = *reinterpret_cast<const bf16x8*>(smB + (size_t)r * 128 + ck * 8);
        }
        #pragma unroll
        for (int rm = 0; rm < 4; ++rm)
            #pragma unroll
            for (int cn = 0; cn < 4; ++cn)
                acc[rm][cn] = __builtin_amdgcn_mfma_f32_16x16x32_bf16(
                    a[rm], b[cn], acc[rm][cn], 0, 0, 0);
    }

    // epilogue: C/D layout col=lane&15, row=(lane>>4)*4+reg  [m89-verified]
    #pragma unroll
    for (int cn = 0; cn < 4; ++cn) {
        int gc = col0 + wn * 64 + cn * 16 + (lane & 15);
        float bias = bcat[gc];
        #pragma unroll
        for (int rm = 0; rm < 4; ++rm) {
            #pragma unroll
            for (int rg = 0; rg < 4; ++rg) {
                int gr = row0 + wm * 64 + rm * 16 + (lane >> 4) * 4 + rg;
                if (gr < n)
                    yb[(size_t)gr * 512 + gc] = f2bf(acc[rm][cn][rg] + bias);
            }
        }
    }
}

// ---------------------------------------------------------------------------
// Counting sort by dst (unchanged)
// ---------------------------------------------------------------------------
__global__ __launch_bounds__(256) void hist_kernel(
    const int* __restrict__ ei, int* __restrict__ count, int E_)
{
    int e = blockIdx.x * 256 + threadIdx.x;
    if (e < E_) atomicAdd(&count[ei[E_ + e]], 1);
}

__global__ __launch_bounds__(256) void bucket_assign(
    const int* __restrict__ count, int* __restrict__ offs,
    int* __restrict__ cursor, int* __restrict__ gcount, int n)
{
    int i = blockIdx.x * 256 + threadIdx.x;
    int lane = threadIdx.x & 63;
    int c = (i < n) ? count[i] : 0;
    int v = c;
    #pragma unroll
    for (int off = 1; off < 64; off <<= 1) {
        int t = __shfl_up(v, off, 64);
        if (lane >= off) v += t;
    }
    int excl  = v - c;
    int total = __shfl(v, 63, 64);
    int base = 0;
    if (lane == 63) base = atomicAdd(gcount, total);
    base = __shfl(base, 63, 64);
    if (i < n) { offs[i] = base + excl; cursor[i] = base + excl; }
}

__global__ __launch_bounds__(256) void scatter_kernel(
    const int* __restrict__ ei, int* __restrict__ cursor,
    int* __restrict__ sorted_src, int E_)
{
    int e = blockIdx.x * 256 + threadIdx.x;
    if (e >= E_) return;
    int src = ei[e];
    int dst = ei[E_ + e];
    int pos = atomicAdd(&cursor[dst], 1);
    sorted_src[pos] = src;
}

// ---------------------------------------------------------------------------
// node_agg on bf16 y: lane holds channels {2l, 2l+1}; lanes 0-31 = head0,
// lanes 32-63 = head1. 5-step xor reduce within 32-lane halves.
// ---------------------------------------------------------------------------
__global__ __launch_bounds__(256) void node_agg(
    const uint* __restrict__ yb32, const int* __restrict__ offs,
    const int* __restrict__ count, const int* __restrict__ sorted_src,
    float* __restrict__ out, int n)
{
    const int node = blockIdx.x * 4 + (threadIdx.x >> 6);
    const int lane = threadIdx.x & 63;
    if (node >= n) return;

    const uint* row = yb32 + (size_t)node * 256;   // 256 uints = 512 bf16
    const uint qw = row[lane];                     // q: uints 0..63
    const float q0 = __uint_as_float(qw << 16);
    const float q1 = __uint_as_float(qw & 0xffff0000u);

    const int deg  = count[node];
    const int base = offs[node];

    float acc0 = 0.f, acc1 = 0.f, den = 0.f;

    int e = 0;
    for (; e + 2 <= deg; e += 2) {
        const uint* ra = yb32 + (size_t)sorted_src[base + e]     * 256;
        const uint* rb = yb32 + (size_t)sorted_src[base + e + 1] * 256;
        uint kwa = ra[64 + lane], vwa = ra[128 + lane];
        uint kwb = rb[64 + lane], vwb = rb[128 + lane];
        float pa = q0 * __uint_as_float(kwa << 16) + q1 * __uint_as_float(kwa & 0xffff0000u);
        float pb = q0 * __uint_as_float(kwb << 16) + q1 * __uint_as_float(kwb & 0xffff0000u);
        #pragma unroll
        for (int off = 16; off > 0; off >>= 1) {
            pa += __shfl_xor(pa, off, 64);
            pb += __shfl_xor(pb, off, 64);
        }
        float aa = __expf(pa * 0.125f);
        float ab = __expf(pb * 0.125f);
        den  += aa + ab;
        acc0 += aa * __uint_as_float(vwa << 16) + ab * __uint_as_float(vwb << 16);
        acc1 += aa * __uint_as_float(vwa & 0xffff0000u) + ab * __uint_as_float(vwb & 0xffff0000u);
    }
    if (e < deg) {
        const uint* ra = yb32 + (size_t)sorted_src[base + e] * 256;
        uint kwa = ra[64 + lane], vwa = ra[128 + lane];
        float pa = q0 * __uint_as_float(kwa << 16) + q1 * __uint_as_float(kwa & 0xffff0000u);
        #pragma unroll
        for (int off = 16; off > 0; off >>= 1)
            pa += __shfl_xor(pa, off, 64);
        float aa = __expf(pa * 0.125f);
        den  += aa;
        acc0 += aa * __uint_as_float(vwa << 16);
        acc1 += aa * __uint_as_float(vwa & 0xffff0000u);
    }

    const float inv = 1.f / fmaxf(den, 1e-16f);
    const uint sw = row[192 + lane];
    float2 o;
    o.x = acc0 * inv + __uint_as_float(sw << 16);
    o.y = acc1 * inv + __uint_as_float(sw & 0xffff0000u);
    *reinterpret_cast<float2*>(out + (size_t)node * 128 + 2 * lane) = o;
}

extern "C" void kernel_launch(void* const* d_in, const int* in_sizes, int n_in,
                              void* d_out, int out_size, void* d_ws, size_t ws_size,
                              hipStream_t stream) {
    const float* x  = (const float*)d_in[0];
    const int*   ei = (const int*)d_in[1];
    const float* Wq = (const float*)d_in[2];
    const float* bq = (const float*)d_in[3];
    const float* Wk = (const float*)d_in[4];
    const float* bk = (const float*)d_in[5];
    const float* Wv = (const float*)d_in[6];
    const float* bv = (const float*)d_in[7];
    const float* Ws = (const float*)d_in[8];
    const float* bs = (const float*)d_in[9];

    const int N = in_sizes[0] / 128;
    const int E = in_sizes[1] / 2;

    ushort* yb    = (ushort*)d_ws;                       // [N][512] bf16
    ushort* xb    = yb + (size_t)N * 512;                // [N][128] bf16
    ushort* WcatT = xb + (size_t)N * 128;                // [512][128] bf16
    float*  bcat  = (float*)(WcatT + 512 * 128);         // [512]
    int* count      = (int*)(bcat + 512);                // [N]
    int* offs       = count + N;                         // [N]
    int* cursor     = offs + N;                          // [N]
    int* gcount     = cursor + N;                        // [1]
    int* sorted_src = gcount + 1;                        // [E]
    float* out      = (float*)d_out;

    hipMemsetAsync(count,  0, (size_t)N * sizeof(int), stream);
    hipMemsetAsync(gcount, 0, sizeof(int), stream);

    conv_x<<<(int)(((long)N * 128 + 2047) / 2048), 256, 0, stream>>>(x, xb, (long)N * 128);
    conv_w<<<256, 256, 0, stream>>>(Wq, bq, Wk, bk, Wv, bv, Ws, bs, WcatT, bcat);

    hist_kernel<<<(E + 255) / 256, 256, 0, stream>>>(ei, count, E);
    bucket_assign<<<(N + 255) / 256, 256, 0, stream>>>(count, offs, cursor, gcount, N);
    scatter_kernel<<<(E + 255) / 256, 256, 0, stream>>>(ei, cursor, sorted_src, E);

    dim3 ggrid(4, (N + 127) / 128);
    qkvs_mfma<<<ggrid, 256, 0, stream>>>(xb, WcatT, bcat, yb, N);

    node_agg<<<(N + 3) / 4, 256, 0, stream>>>((const uint*)yb, offs, count, sorted_src, out, N);
}

// Round 4
// 201.667 us; speedup vs baseline: 3.1426x; 1.1584x over previous
//
#include <hip/hip_runtime.h>
#include <hip/hip_bf16.h>

typedef __attribute__((ext_vector_type(4))) float f32x4;
typedef __attribute__((ext_vector_type(8))) short bf16x8;   // 8 bf16 in 4 VGPRs

#define AS1 __attribute__((address_space(1)))
#define AS3 __attribute__((address_space(3)))

static __device__ __forceinline__ ushort f2bf(float v) {
    __hip_bfloat16 h = __float2bfloat16(v);
    return *reinterpret_cast<ushort*>(&h);
}
static __device__ __forceinline__ float bl(uint u) { return __uint_as_float(u << 16); }
static __device__ __forceinline__ float bh(uint u) { return __uint_as_float(u & 0xffff0000u); }

// ---------------------------------------------------------------------------
// convert x (fp32) -> xb (bf16), 8 elems/thread
// ---------------------------------------------------------------------------
__global__ __launch_bounds__(256) void conv_x(
    const float* __restrict__ x, ushort* __restrict__ xb, long total)
{
    long id = (long)blockIdx.x * 256 + threadIdx.x;
    long base = id * 8;
    if (base >= total) return;
    f32x4 a = *reinterpret_cast<const f32x4*>(x + base);
    f32x4 b = *reinterpret_cast<const f32x4*>(x + base + 4);
    uint4 o;
    o.x = (uint)f2bf(a[0]) | ((uint)f2bf(a[1]) << 16);
    o.y = (uint)f2bf(a[2]) | ((uint)f2bf(a[3]) << 16);
    o.z = (uint)f2bf(b[0]) | ((uint)f2bf(b[1]) << 16);
    o.w = (uint)f2bf(b[2]) | ((uint)f2bf(b[3]) << 16);
    *reinterpret_cast<uint4*>(xb + base) = o;
}

// ---------------------------------------------------------------------------
// Build WcatT[newcol 0..511][k 0..127] bf16 + bcat[512] fp32.
// NEW column order: [ q(0..127) | kv-interleaved: k0 k1 v0 v1 k2 k3 v2 v3 ...
// (256 cols) | skip(0..127) ]  -> node_agg reads k,v as one dwordx2/lane.
// ---------------------------------------------------------------------------
__global__ __launch_bounds__(256) void conv_w(
    const float* __restrict__ Wq, const float* __restrict__ bq,
    const float* __restrict__ Wk, const float* __restrict__ bk,
    const float* __restrict__ Wv, const float* __restrict__ bv,
    const float* __restrict__ Ws, const float* __restrict__ bs,
    ushort* __restrict__ WcatT, float* __restrict__ bcat)
{
    int id = blockIdx.x * 256 + threadIdx.x;   // 65536 threads
    int r = id >> 7, k = id & 127;             // r = new col, k = reduction idx
    int which, c;
    if (r < 128)      { which = 0; c = r; }
    else if (r < 384) { int j = r - 128; which = ((j & 3) < 2) ? 1 : 2;
                        c = ((j >> 2) << 1) + (j & 1); }
    else              { which = 3; c = r - 384; }
    const float* W = (which == 0) ? Wq : (which == 1) ? Wk : (which == 2) ? Wv : Ws;
    WcatT[(size_t)r * 128 + k] = f2bf(W[(size_t)k * 128 + c]);
    if (k == 0) {
        const float* b = (which == 0) ? bq : (which == 1) ? bk : (which == 2) ? bv : bs;
        bcat[r] = b[c];
    }
}

// ---------------------------------------------------------------------------
// MFMA GEMM: yb[n][512] = bf16( xb[n][128] @ WcatT^T + bcat )
// 128x128 tile, 4 waves x (64x64), K=128 in LDS; epilogue repacks C through
// LDS (swizzled f32) and stores 16B/lane coalesced.
// ---------------------------------------------------------------------------
__global__ __launch_bounds__(256) void qkvs_mfma(
    const ushort* __restrict__ xb, const ushort* __restrict__ WcatT,
    const float* __restrict__ bcat, ushort* __restrict__ yb, int n)
{
    __shared__ ushort sm[32768];        // 64 KB total
    ushort* smA = sm;                   // 128x128 bf16, chunk-swizzled
    ushort* smB = sm + 16384;

    const int t    = threadIdx.x;
    const int lane = t & 63;
    const int w    = t >> 6;
    const int wm   = w >> 1, wn = w & 1;
    const int row0 = blockIdx.y * 128;
    const int col0 = blockIdx.x * 128;

    #pragma unroll
    for (int i = 0; i < 8; ++i) {
        int L = i * 256 + t;
        int r = L >> 4, ck = L & 15;
        int gr = min(row0 + r, n - 1);
        const ushort* gpA = xb + (size_t)gr * 128 + ((ck ^ (r & 7)) << 3);
        __builtin_amdgcn_global_load_lds((const AS1 void*)gpA,
            (AS3 void*)(smA + (size_t)(i * 256 + (t & 192)) * 8), 16, 0, 0);
        const ushort* gpB = WcatT + (size_t)(col0 + r) * 128 + ((ck ^ (r & 7)) << 3);
        __builtin_amdgcn_global_load_lds((const AS1 void*)gpB,
            (AS3 void*)(smB + (size_t)(i * 256 + (t & 192)) * 8), 16, 0, 0);
    }
    __syncthreads();

    f32x4 acc[4][4];
    #pragma unroll
    for (int i = 0; i < 4; ++i)
        #pragma unroll
        for (int j = 0; j < 4; ++j) acc[i][j] = (f32x4)(0.f);

    #pragma unroll
    for (int kb = 0; kb < 128; kb += 32) {
        const int kc = kb >> 3;
        bf16x8 a[4], b[4];
        #pragma unroll
        for (int rm = 0; rm < 4; ++rm) {
            int r  = wm * 64 + rm * 16 + (lane & 15);
            int ck = (kc + (lane >> 4)) ^ (r & 7);
            a[rm] = *reinterpret_cast<const bf16x8*>(smA + (size_t)r * 128 + ck * 8);
        }
        #pragma unroll
        for (int cn = 0; cn < 4; ++cn) {
            int r  = wn * 64 + cn * 16 + (lane & 15);
            int ck = (kc + (lane >> 4)) ^ (r & 7);
            b[cn] = *reinterpret_cast<const bf16x8*>(smB + (size_t)r * 128 + ck * 8);
        }
        #pragma unroll
        for (int rm = 0; rm < 4; ++rm)
            #pragma unroll
            for (int cn = 0; cn < 4; ++cn)
                acc[rm][cn] = __builtin_amdgcn_mfma_f32_16x16x32_bf16(
                    a[rm], b[cn], acc[rm][cn], 0, 0, 0);
    }

    // ---- epilogue: acc -> LDS (f32, col-swizzled) -> bf16 packed stores ----
    __syncthreads();                    // all waves done reading smA/smB
    float* lf = reinterpret_cast<float*>(sm);   // 128x128 f32 view (64 KB)

    #pragma unroll
    for (int cn = 0; cn < 4; ++cn) {
        int lc = wn * 64 + cn * 16 + (lane & 15);
        float bias = bcat[col0 + lc];
        #pragma unroll
        for (int rm = 0; rm < 4; ++rm) {
            int R = wm * 64 + rm * 16 + (lane >> 4) * 4;
            #pragma unroll
            for (int rg = 0; rg < 4; ++rg) {
                int r = R + rg;
                lf[r * 128 + (lc ^ ((r & 7) << 2))] = acc[rm][cn][rg] + bias;
            }
        }
    }
    __syncthreads();

    #pragma unroll
    for (int i = 0; i < 8; ++i) {
        int r   = w * 32 + i * 4 + (lane >> 4);
        int c0  = (lane & 15) * 8;
        int swz = (r & 7) << 2;
        int gr  = row0 + r;
        if (gr < n) {
            f32x4 lo = *reinterpret_cast<const f32x4*>(&lf[r * 128 + (c0 ^ swz)]);
            f32x4 hi = *reinterpret_cast<const f32x4*>(&lf[r * 128 + ((c0 + 4) ^ swz)]);
            uint4 o;
            o.x = (uint)f2bf(lo[0]) | ((uint)f2bf(lo[1]) << 16);
            o.y = (uint)f2bf(lo[2]) | ((uint)f2bf(lo[3]) << 16);
            o.z = (uint)f2bf(hi[0]) | ((uint)f2bf(hi[1]) << 16);
            o.w = (uint)f2bf(hi[2]) | ((uint)f2bf(hi[3]) << 16);
            *reinterpret_cast<uint4*>(yb + (size_t)gr * 512 + col0 + c0) = o;
        }
    }
}

// ---------------------------------------------------------------------------
// Counting sort by dst — 4 edges/thread, int4 reads
// ---------------------------------------------------------------------------
__global__ __launch_bounds__(256) void hist_kernel(
    const int* __restrict__ ei, int* __restrict__ count, int E_)
{
    int b = (blockIdx.x * 256 + threadIdx.x) * 4;
    if (b + 4 <= E_) {
        int4 d = *reinterpret_cast<const int4*>(ei + E_ + b);
        atomicAdd(&count[d.x], 1); atomicAdd(&count[d.y], 1);
        atomicAdd(&count[d.z], 1); atomicAdd(&count[d.w], 1);
    } else {
        for (int j = b; j < E_; ++j) atomicAdd(&count[ei[E_ + j]], 1);
    }
}

__global__ __launch_bounds__(256) void bucket_assign(
    const int* __restrict__ count, int* __restrict__ offs,
    int* __restrict__ cursor, int* __restrict__ gcount, int n)
{
    int i = blockIdx.x * 256 + threadIdx.x;
    int lane = threadIdx.x & 63;
    int c = (i < n) ? count[i] : 0;
    int v = c;
    #pragma unroll
    for (int off = 1; off < 64; off <<= 1) {
        int t = __shfl_up(v, off, 64);
        if (lane >= off) v += t;
    }
    int excl  = v - c;
    int total = __shfl(v, 63, 64);
    int base = 0;
    if (lane == 63) base = atomicAdd(gcount, total);
    base = __shfl(base, 63, 64);
    if (i < n) { offs[i] = base + excl; cursor[i] = base + excl; }
}

__global__ __launch_bounds__(256) void scatter_kernel(
    const int* __restrict__ ei, int* __restrict__ cursor,
    int* __restrict__ sorted_src, int E_)
{
    int b = (blockIdx.x * 256 + threadIdx.x) * 4;
    if (b + 4 <= E_) {
        int4 s = *reinterpret_cast<const int4*>(ei + b);
        int4 d = *reinterpret_cast<const int4*>(ei + E_ + b);
        sorted_src[atomicAdd(&cursor[d.x], 1)] = s.x;
        sorted_src[atomicAdd(&cursor[d.y], 1)] = s.y;
        sorted_src[atomicAdd(&cursor[d.z], 1)] = s.z;
        sorted_src[atomicAdd(&cursor[d.w], 1)] = s.w;
    } else {
        for (int j = b; j < E_; ++j)
            sorted_src[atomicAdd(&cursor[ei[E_ + j]], 1)] = ei[j];
    }
}

// ---------------------------------------------------------------------------
// node_agg: one wave per dst. kv-interleaved y -> one dwordx2/lane per edge;
// unroll 4 edges (4 independent load+reduce chains).
// ---------------------------------------------------------------------------
__global__ __launch_bounds__(256) void node_agg(
    const uint* __restrict__ yb32, const int* __restrict__ offs,
    const int* __restrict__ count, const int* __restrict__ sorted_src,
    float* __restrict__ out, int n)
{
    const int node = blockIdx.x * 4 + (threadIdx.x >> 6);
    const int lane = threadIdx.x & 63;
    if (node >= n) return;

    const uint* row = yb32 + (size_t)node * 256;   // q:0..63 | kv:64..191 | skip:192..255
    const uint qw = row[lane];
    const uint sw = row[192 + lane];               // skip, loaded early
    const float q0 = bl(qw) * 0.125f;              // fold 1/sqrt(C) into q
    const float q1 = bh(qw) * 0.125f;

    const int deg  = count[node];
    const int* sp  = sorted_src + offs[node];

    float acc0 = 0.f, acc1 = 0.f, den = 0.f;

    int e = 0;
    for (; e + 4 <= deg; e += 4) {
        const int s0 = sp[e], s1 = sp[e + 1], s2 = sp[e + 2], s3 = sp[e + 3];
        uint2 kv0 = *reinterpret_cast<const uint2*>(yb32 + (size_t)s0 * 256 + 64 + 2 * lane);
        uint2 kv1 = *reinterpret_cast<const uint2*>(yb32 + (size_t)s1 * 256 + 64 + 2 * lane);
        uint2 kv2 = *reinterpret_cast<const uint2*>(yb32 + (size_t)s2 * 256 + 64 + 2 * lane);
        uint2 kv3 = *reinterpret_cast<const uint2*>(yb32 + (size_t)s3 * 256 + 64 + 2 * lane);
        float p0 = q0 * bl(kv0.x) + q1 * bh(kv0.x);
        float p1 = q0 * bl(kv1.x) + q1 * bh(kv1.x);
        float p2 = q0 * bl(kv2.x) + q1 * bh(kv2.x);
        float p3 = q0 * bl(kv3.x) + q1 * bh(kv3.x);
        #pragma unroll
        for (int off = 16; off > 0; off >>= 1) {
            p0 += __shfl_xor(p0, off, 64);
            p1 += __shfl_xor(p1, off, 64);
            p2 += __shfl_xor(p2, off, 64);
            p3 += __shfl_xor(p3, off, 64);
        }
        float a0 = __expf(p0), a1 = __expf(p1), a2 = __expf(p2), a3 = __expf(p3);
        den  += (a0 + a1) + (a2 + a3);
        acc0 += a0 * bl(kv0.y) + a1 * bl(kv1.y) + a2 * bl(kv2.y) + a3 * bl(kv3.y);
        acc1 += a0 * bh(kv0.y) + a1 * bh(kv1.y) + a2 * bh(kv2.y) + a3 * bh(kv3.y);
    }
    for (; e < deg; ++e) {
        const int s0 = sp[e];
        uint2 kv = *reinterpret_cast<const uint2*>(yb32 + (size_t)s0 * 256 + 64 + 2 * lane);
        float p = q0 * bl(kv.x) + q1 * bh(kv.x);
        #pragma unroll
        for (int off = 16; off > 0; off >>= 1)
            p += __shfl_xor(p, off, 64);
        float a = __expf(p);
        den  += a;
        acc0 += a * bl(kv.y);
        acc1 += a * bh(kv.y);
    }

    const float inv = 1.f / fmaxf(den, 1e-16f);
    float2 o;
    o.x = acc0 * inv + bl(sw);
    o.y = acc1 * inv + bh(sw);
    *reinterpret_cast<float2*>(out + (size_t)node * 128 + 2 * lane) = o;
}

extern "C" void kernel_launch(void* const* d_in, const int* in_sizes, int n_in,
                              void* d_out, int out_size, void* d_ws, size_t ws_size,
                              hipStream_t stream) {
    const float* x  = (const float*)d_in[0];
    const int*   ei = (const int*)d_in[1];
    const float* Wq = (const float*)d_in[2];
    const float* bq = (const float*)d_in[3];
    const float* Wk = (const float*)d_in[4];
    const float* bk = (const float*)d_in[5];
    const float* Wv = (const float*)d_in[6];
    const float* bv = (const float*)d_in[7];
    const float* Ws = (const float*)d_in[8];
    const float* bs = (const float*)d_in[9];

    const int N = in_sizes[0] / 128;
    const int E = in_sizes[1] / 2;

    ushort* yb    = (ushort*)d_ws;                       // [N][512] bf16
    ushort* xb    = yb + (size_t)N * 512;                // [N][128] bf16
    ushort* WcatT = xb + (size_t)N * 128;                // [512][128] bf16
    float*  bcat  = (float*)(WcatT + 512 * 128);         // [512]
    int* count      = (int*)(bcat + 512);                // [N]
    int* offs       = count + N;                         // [N]
    int* cursor     = offs + N;                          // [N]
    int* gcount     = cursor + N;                        // [1]
    int* sorted_src = gcount + 1;                        // [E]
    float* out      = (float*)d_out;

    hipMemsetAsync(count,  0, (size_t)N * sizeof(int), stream);
    hipMemsetAsync(gcount, 0, sizeof(int), stream);

    conv_x<<<(int)(((long)N * 128 + 2047) / 2048), 256, 0, stream>>>(x, xb, (long)N * 128);
    conv_w<<<256, 256, 0, stream>>>(Wq, bq, Wk, bk, Wv, bv, Ws, bs, WcatT, bcat);

    hist_kernel<<<(E / 4 + 255) / 256, 256, 0, stream>>>(ei, count, E);
    bucket_assign<<<(N + 255) / 256, 256, 0, stream>>>(count, offs, cursor, gcount, N);
    scatter_kernel<<<(E / 4 + 255) / 256, 256, 0, stream>>>(ei, cursor, sorted_src, E);

    dim3 ggrid(4, (N + 127) / 128);
    qkvs_mfma<<<ggrid, 256, 0, stream>>>(xb, WcatT, bcat, yb, N);

    node_agg<<<(N + 3) / 4, 256, 0, stream>>>((const uint*)yb, offs, count, sorted_src, out, N);
}

// Round 5
// 194.820 us; speedup vs baseline: 3.2530x; 1.0351x over previous
//
#include <hip/hip_runtime.h>
#include <hip/hip_bf16.h>

typedef __attribute__((ext_vector_type(4))) float f32x4;
typedef __attribute__((ext_vector_type(8))) short bf16x8;   // 8 bf16 in 4 VGPRs

#define AS1 __attribute__((address_space(1)))
#define AS3 __attribute__((address_space(3)))

static __device__ __forceinline__ ushort f2bf(float v) {
    __hip_bfloat16 h = __float2bfloat16(v);
    return *reinterpret_cast<ushort*>(&h);
}
static __device__ __forceinline__ float bl(uint u) { return __uint_as_float(u << 16); }
static __device__ __forceinline__ float bh(uint u) { return __uint_as_float(u & 0xffff0000u); }

// ---------------------------------------------------------------------------
// Setup: blocks [0,256) build WcatT (bf16, transposed, kv-interleaved column
// order: q | k0 k1 v0 v1 ... | skip) + bcat; blocks [256,...) do dst histogram.
// ---------------------------------------------------------------------------
__global__ __launch_bounds__(256) void setup_kernel(
    const float* __restrict__ Wq, const float* __restrict__ bq,
    const float* __restrict__ Wk, const float* __restrict__ bk,
    const float* __restrict__ Wv, const float* __restrict__ bv,
    const float* __restrict__ Ws, const float* __restrict__ bs,
    ushort* __restrict__ WcatT, float* __restrict__ bcat,
    const int* __restrict__ ei, int* __restrict__ count, int E_)
{
    const int bid = blockIdx.x;
    if (bid < 256) {
        int id = bid * 256 + threadIdx.x;      // 65536 = 512 cols x 128 k
        int r = id >> 7, k = id & 127;
        int which, c;
        if (r < 128)      { which = 0; c = r; }
        else if (r < 384) { int j = r - 128; which = ((j & 3) < 2) ? 1 : 2;
                            c = ((j >> 2) << 1) + (j & 1); }
        else              { which = 3; c = r - 384; }
        const float* W = (which == 0) ? Wq : (which == 1) ? Wk : (which == 2) ? Wv : Ws;
        WcatT[(size_t)r * 128 + k] = f2bf(W[(size_t)k * 128 + c]);
        if (k == 0) {
            const float* b = (which == 0) ? bq : (which == 1) ? bk : (which == 2) ? bv : bs;
            bcat[r] = b[c];
        }
    } else {
        int b = ((bid - 256) * 256 + threadIdx.x) * 4;
        if (b + 4 <= E_) {
            int4 d = *reinterpret_cast<const int4*>(ei + E_ + b);
            atomicAdd(&count[d.x], 1); atomicAdd(&count[d.y], 1);
            atomicAdd(&count[d.z], 1); atomicAdd(&count[d.w], 1);
        } else {
            for (int j = b; j < E_; ++j) atomicAdd(&count[ei[E_ + j]], 1);
        }
    }
}

// ---------------------------------------------------------------------------
// Fused conv+GEMM: yb[n][512] = bf16( x[n][128] @ WcatT^T + bcat ).
// One block per 128-row stripe; A staged once (fp32 -> bf16 in regs, swizzled
// ds_write); loop over 4 column tiles: B via global_load_lds, MFMA, C packed
// bf16 into the B buffer, coalesced uint4 stores. LDS = 64 KB.
// ---------------------------------------------------------------------------
__global__ __launch_bounds__(256) void qkvs_mfma(
    const float* __restrict__ x, const ushort* __restrict__ WcatT,
    const float* __restrict__ bcat, ushort* __restrict__ yb, int n)
{
    __shared__ ushort smA[16384];   // 32 KB: 128 rows x 128 k bf16, chunk-swizzled
    __shared__ ushort smB[16384];   // 32 KB: B tile / C-bf16 repack (reused)

    const int t    = threadIdx.x;
    const int lane = t & 63;
    const int w    = t >> 6;
    const int wm   = w >> 1, wn = w & 1;
    const int row0 = blockIdx.x * 128;

    // ---- stage A once: read fp32 x, convert, swizzled ds_write_b128 ----
    #pragma unroll
    for (int i = 0; i < 8; ++i) {
        int L = i * 256 + t;
        int r = L >> 4, ck = L & 15;
        int gr = min(row0 + r, n - 1);
        const float* gp = x + (size_t)gr * 128 + ck * 8;
        f32x4 lo = *reinterpret_cast<const f32x4*>(gp);
        f32x4 hi = *reinterpret_cast<const f32x4*>(gp + 4);
        uint4 o;
        o.x = (uint)f2bf(lo[0]) | ((uint)f2bf(lo[1]) << 16);
        o.y = (uint)f2bf(lo[2]) | ((uint)f2bf(lo[3]) << 16);
        o.z = (uint)f2bf(hi[0]) | ((uint)f2bf(hi[1]) << 16);
        o.w = (uint)f2bf(hi[2]) | ((uint)f2bf(hi[3]) << 16);
        *reinterpret_cast<uint4*>(smA + (size_t)r * 128 + ((ck ^ (r & 7)) << 3)) = o;
    }

    for (int ct = 0; ct < 4; ++ct) {
        __syncthreads();   // smB free (prev readback done); 1st iter: pairs with A
        #pragma unroll
        for (int i = 0; i < 8; ++i) {
            int L = i * 256 + t;
            int r = L >> 4, ck = L & 15;
            const ushort* gpB = WcatT + (size_t)(ct * 128 + r) * 128 + ((ck ^ (r & 7)) << 3);
            __builtin_amdgcn_global_load_lds((const AS1 void*)gpB,
                (AS3 void*)(smB + (size_t)(i * 256 + (t & 192)) * 8), 16, 0, 0);
        }
        __syncthreads();

        f32x4 acc[4][4];
        #pragma unroll
        for (int i = 0; i < 4; ++i)
            #pragma unroll
            for (int j = 0; j < 4; ++j) acc[i][j] = (f32x4)(0.f);

        #pragma unroll
        for (int kb = 0; kb < 4; ++kb) {
            bf16x8 a[4], b[4];
            #pragma unroll
            for (int rm = 0; rm < 4; ++rm) {
                int r  = wm * 64 + rm * 16 + (lane & 15);
                int ck = (kb * 4 + (lane >> 4)) ^ (r & 7);
                a[rm] = *reinterpret_cast<const bf16x8*>(smA + (size_t)r * 128 + ck * 8);
            }
            #pragma unroll
            for (int cn = 0; cn < 4; ++cn) {
                int r  = wn * 64 + cn * 16 + (lane & 15);
                int ck = (kb * 4 + (lane >> 4)) ^ (r & 7);
                b[cn] = *reinterpret_cast<const bf16x8*>(smB + (size_t)r * 128 + ck * 8);
            }
            #pragma unroll
            for (int rm = 0; rm < 4; ++rm)
                #pragma unroll
                for (int cn = 0; cn < 4; ++cn)
                    acc[rm][cn] = __builtin_amdgcn_mfma_f32_16x16x32_bf16(
                        a[rm], b[cn], acc[rm][cn], 0, 0, 0);
        }

        __syncthreads();   // all waves done reading smB
        // pack C (+bias) as bf16 into smB, chunk-swizzled rows
        #pragma unroll
        for (int cn = 0; cn < 4; ++cn) {
            int lc = wn * 64 + cn * 16 + (lane & 15);
            float bias = bcat[ct * 128 + lc];
            #pragma unroll
            for (int rm = 0; rm < 4; ++rm) {
                int R = wm * 64 + rm * 16 + (lane >> 4) * 4;
                #pragma unroll
                for (int rg = 0; rg < 4; ++rg) {
                    int r = R + rg;
                    int addr = r * 128 + ((((lc >> 3) ^ (r & 7)) << 3) | (lc & 7));
                    smB[addr] = f2bf(acc[rm][cn][rg] + bias);
                }
            }
        }
        __syncthreads();
        // coalesced readback + store: 8 uint4/thread
        #pragma unroll
        for (int i = 0; i < 8; ++i) {
            int L = i * 256 + t;
            int r = L >> 4, c16 = L & 15;
            int gr = row0 + r;
            if (gr < n) {
                uint4 o = *reinterpret_cast<const uint4*>(
                    smB + (size_t)r * 128 + ((c16 ^ (r & 7)) << 3));
                *reinterpret_cast<uint4*>(yb + (size_t)gr * 512 + ct * 128 + c16 * 8) = o;
            }
        }
    }
}

// ---------------------------------------------------------------------------
// Counting sort (bucket_assign + scatter)
// ---------------------------------------------------------------------------
__global__ __launch_bounds__(256) void bucket_assign(
    const int* __restrict__ count, int* __restrict__ offs,
    int* __restrict__ cursor, int* __restrict__ gcount, int n)
{
    int i = blockIdx.x * 256 + threadIdx.x;
    int lane = threadIdx.x & 63;
    int c = (i < n) ? count[i] : 0;
    int v = c;
    #pragma unroll
    for (int off = 1; off < 64; off <<= 1) {
        int t = __shfl_up(v, off, 64);
        if (lane >= off) v += t;
    }
    int excl  = v - c;
    int total = __shfl(v, 63, 64);
    int base = 0;
    if (lane == 63) base = atomicAdd(gcount, total);
    base = __shfl(base, 63, 64);
    if (i < n) { offs[i] = base + excl; cursor[i] = base + excl; }
}

__global__ __launch_bounds__(256) void scatter_kernel(
    const int* __restrict__ ei, int* __restrict__ cursor,
    int* __restrict__ sorted_src, int E_)
{
    int b = (blockIdx.x * 256 + threadIdx.x) * 4;
    if (b + 4 <= E_) {
        int4 s = *reinterpret_cast<const int4*>(ei + b);
        int4 d = *reinterpret_cast<const int4*>(ei + E_ + b);
        sorted_src[atomicAdd(&cursor[d.x], 1)] = s.x;
        sorted_src[atomicAdd(&cursor[d.y], 1)] = s.y;
        sorted_src[atomicAdd(&cursor[d.z], 1)] = s.z;
        sorted_src[atomicAdd(&cursor[d.w], 1)] = s.w;
    } else {
        for (int j = b; j < E_; ++j)
            sorted_src[atomicAdd(&cursor[ei[E_ + j]], 1)] = ei[j];
    }
}

// ---------------------------------------------------------------------------
// node_agg: one wave per dst; kv-interleaved y -> one dwordx2/lane per edge;
// unroll 8 -> 8 independent load+reduce chains in flight.
// ---------------------------------------------------------------------------
__global__ __launch_bounds__(256) void node_agg(
    const uint* __restrict__ yb32, const int* __restrict__ offs,
    const int* __restrict__ count, const int* __restrict__ sorted_src,
    float* __restrict__ out, int n)
{
    const int node = blockIdx.x * 4 + (threadIdx.x >> 6);
    const int lane = threadIdx.x & 63;
    if (node >= n) return;

    const uint* row = yb32 + (size_t)node * 256;   // q:0..63 | kv:64..191 | skip:192..255
    const uint qw = row[lane];
    const uint sw = row[192 + lane];
    const float q0 = bl(qw) * 0.125f;
    const float q1 = bh(qw) * 0.125f;

    const int deg  = count[node];
    const int* sp  = sorted_src + offs[node];

    float acc0 = 0.f, acc1 = 0.f, den = 0.f;

    int e = 0;
    for (; e + 8 <= deg; e += 8) {
        int s[8];
        #pragma unroll
        for (int j = 0; j < 8; ++j) s[j] = sp[e + j];
        uint2 kv[8];
        #pragma unroll
        for (int j = 0; j < 8; ++j)
            kv[j] = *reinterpret_cast<const uint2*>(yb32 + (size_t)s[j] * 256 + 64 + 2 * lane);
        float p[8];
        #pragma unroll
        for (int j = 0; j < 8; ++j) p[j] = q0 * bl(kv[j].x) + q1 * bh(kv[j].x);
        #pragma unroll
        for (int off = 16; off > 0; off >>= 1) {
            #pragma unroll
            for (int j = 0; j < 8; ++j) p[j] += __shfl_xor(p[j], off, 64);
        }
        #pragma unroll
        for (int j = 0; j < 8; ++j) {
            float a = __expf(p[j]);
            den  += a;
            acc0 += a * bl(kv[j].y);
            acc1 += a * bh(kv[j].y);
        }
    }
    if (e + 4 <= deg) {
        int s[4];
        #pragma unroll
        for (int j = 0; j < 4; ++j) s[j] = sp[e + j];
        uint2 kv[4];
        #pragma unroll
        for (int j = 0; j < 4; ++j)
            kv[j] = *reinterpret_cast<const uint2*>(yb32 + (size_t)s[j] * 256 + 64 + 2 * lane);
        float p[4];
        #pragma unroll
        for (int j = 0; j < 4; ++j) p[j] = q0 * bl(kv[j].x) + q1 * bh(kv[j].x);
        #pragma unroll
        for (int off = 16; off > 0; off >>= 1) {
            #pragma unroll
            for (int j = 0; j < 4; ++j) p[j] += __shfl_xor(p[j], off, 64);
        }
        #pragma unroll
        for (int j = 0; j < 4; ++j) {
            float a = __expf(p[j]);
            den  += a;
            acc0 += a * bl(kv[j].y);
            acc1 += a * bh(kv[j].y);
        }
        e += 4;
    }
    for (; e < deg; ++e) {
        uint2 kv = *reinterpret_cast<const uint2*>(yb32 + (size_t)sp[e] * 256 + 64 + 2 * lane);
        float p = q0 * bl(kv.x) + q1 * bh(kv.x);
        #pragma unroll
        for (int off = 16; off > 0; off >>= 1)
            p += __shfl_xor(p, off, 64);
        float a = __expf(p);
        den  += a;
        acc0 += a * bl(kv.y);
        acc1 += a * bh(kv.y);
    }

    const float inv = 1.f / fmaxf(den, 1e-16f);
    float2 o;
    o.x = acc0 * inv + bl(sw);
    o.y = acc1 * inv + bh(sw);
    *reinterpret_cast<float2*>(out + (size_t)node * 128 + 2 * lane) = o;
}

extern "C" void kernel_launch(void* const* d_in, const int* in_sizes, int n_in,
                              void* d_out, int out_size, void* d_ws, size_t ws_size,
                              hipStream_t stream) {
    const float* x  = (const float*)d_in[0];
    const int*   ei = (const int*)d_in[1];
    const float* Wq = (const float*)d_in[2];
    const float* bq = (const float*)d_in[3];
    const float* Wk = (const float*)d_in[4];
    const float* bk = (const float*)d_in[5];
    const float* Wv = (const float*)d_in[6];
    const float* bv = (const float*)d_in[7];
    const float* Ws = (const float*)d_in[8];
    const float* bs = (const float*)d_in[9];

    const int N = in_sizes[0] / 128;
    const int E = in_sizes[1] / 2;

    ushort* yb    = (ushort*)d_ws;                       // [N][512] bf16
    ushort* WcatT = yb + (size_t)N * 512;                // [512][128] bf16
    float*  bcat  = (float*)(WcatT + 512 * 128);         // [512]
    int* count      = (int*)(bcat + 512);                // [N]
    int* gcount     = count + N;                         // [1]
    int* offs       = gcount + 1;                        // [N]
    int* cursor     = offs + N;                          // [N]
    int* sorted_src = cursor + N;                        // [E]
    float* out      = (float*)d_out;

    hipMemsetAsync(count, 0, (size_t)(N + 1) * sizeof(int), stream);  // count+gcount

    const int histBlocks = (E / 4 + 255) / 256;
    setup_kernel<<<256 + histBlocks, 256, 0, stream>>>(
        Wq, bq, Wk, bk, Wv, bv, Ws, bs, WcatT, bcat, ei, count, E);

    bucket_assign<<<(N + 255) / 256, 256, 0, stream>>>(count, offs, cursor, gcount, N);
    scatter_kernel<<<(E / 4 + 255) / 256, 256, 0, stream>>>(ei, cursor, sorted_src, E);

    qkvs_mfma<<<(N + 127) / 128, 256, 0, stream>>>(x, WcatT, bcat, yb, N);

    node_agg<<<(N + 3) / 4, 256, 0, stream>>>((const uint*)yb, offs, count, sorted_src, out, N);
}

// Round 6
// 182.650 us; speedup vs baseline: 3.4698x; 1.0666x over previous
//
#include <hip/hip_runtime.h>
#include <hip/hip_bf16.h>

typedef __attribute__((ext_vector_type(4))) float f32x4;
typedef __attribute__((ext_vector_type(8))) short bf16x8;   // 8 bf16 in 4 VGPRs

#define AS1 __attribute__((address_space(1)))
#define AS3 __attribute__((address_space(3)))

static __device__ __forceinline__ ushort f2bf(float v) {
    __hip_bfloat16 h = __float2bfloat16(v);
    return *reinterpret_cast<ushort*>(&h);
}
static __device__ __forceinline__ float bl(uint u) { return __uint_as_float(u << 16); }
static __device__ __forceinline__ float bh(uint u) { return __uint_as_float(u & 0xffff0000u); }

// ---------------------------------------------------------------------------
// Setup: blocks [0,256) build WcatT (bf16, transposed, kv-interleaved column
// order: q | k0 k1 v0 v1 ... | skip) + bcat; blocks [256,...) do dst histogram.
// ---------------------------------------------------------------------------
__global__ __launch_bounds__(256) void setup_kernel(
    const float* __restrict__ Wq, const float* __restrict__ bq,
    const float* __restrict__ Wk, const float* __restrict__ bk,
    const float* __restrict__ Wv, const float* __restrict__ bv,
    const float* __restrict__ Ws, const float* __restrict__ bs,
    ushort* __restrict__ WcatT, float* __restrict__ bcat,
    const int* __restrict__ ei, int* __restrict__ count, int E_)
{
    const int bid = blockIdx.x;
    if (bid < 256) {
        int id = bid * 256 + threadIdx.x;      // 65536 = 512 cols x 128 k
        int r = id >> 7, k = id & 127;
        int which, c;
        if (r < 128)      { which = 0; c = r; }
        else if (r < 384) { int j = r - 128; which = ((j & 3) < 2) ? 1 : 2;
                            c = ((j >> 2) << 1) + (j & 1); }
        else              { which = 3; c = r - 384; }
        const float* W = (which == 0) ? Wq : (which == 1) ? Wk : (which == 2) ? Wv : Ws;
        WcatT[(size_t)r * 128 + k] = f2bf(W[(size_t)k * 128 + c]);
        if (k == 0) {
            const float* b = (which == 0) ? bq : (which == 1) ? bk : (which == 2) ? bv : bs;
            bcat[r] = b[c];
        }
    } else {
        int b = ((bid - 256) * 256 + threadIdx.x) * 4;
        if (b + 4 <= E_) {
            int4 d = *reinterpret_cast<const int4*>(ei + E_ + b);
            atomicAdd(&count[d.x], 1); atomicAdd(&count[d.y], 1);
            atomicAdd(&count[d.z], 1); atomicAdd(&count[d.w], 1);
        } else {
            for (int j = b; j < E_; ++j) atomicAdd(&count[ei[E_ + j]], 1);
        }
    }
}

// ---------------------------------------------------------------------------
// bucket_assign: exclusive prefix over counts -> offs, cursor
// ---------------------------------------------------------------------------
__global__ __launch_bounds__(256) void bucket_assign(
    const int* __restrict__ count, int* __restrict__ offs,
    int* __restrict__ cursor, int* __restrict__ gcount, int n)
{
    int i = blockIdx.x * 256 + threadIdx.x;
    int lane = threadIdx.x & 63;
    int c = (i < n) ? count[i] : 0;
    int v = c;
    #pragma unroll
    for (int off = 1; off < 64; off <<= 1) {
        int t = __shfl_up(v, off, 64);
        if (lane >= off) v += t;
    }
    int excl  = v - c;
    int total = __shfl(v, 63, 64);
    int base = 0;
    if (lane == 63) base = atomicAdd(gcount, total);
    base = __shfl(base, 63, 64);
    if (i < n) { offs[i] = base + excl; cursor[i] = base + excl; }
}

// ---------------------------------------------------------------------------
// fused_mid: blocks [0,nScat) = scatter (8 edges/thread);
//            blocks [nScat,..) = conv+MFMA GEMM (independent -> overlap).
// Scatter blocks first so the long GEMM blocks stream in behind them.
// ---------------------------------------------------------------------------
__global__ __launch_bounds__(256) void fused_mid(
    const float* __restrict__ x, const ushort* __restrict__ WcatT,
    const float* __restrict__ bcat, ushort* __restrict__ yb, int n,
    const int* __restrict__ ei, int* __restrict__ cursor,
    int* __restrict__ sorted_src, int E_, int nScat)
{
    __shared__ ushort smA[16384];   // 32 KB: 128x128 bf16, chunk-swizzled
    __shared__ ushort smB[16384];   // 32 KB: B tile / C repack

    const int t = threadIdx.x;

    if ((int)blockIdx.x < nScat) {
        int b = ((int)blockIdx.x * 256 + t) * 8;
        if (b + 8 <= E_) {
            int4 s0 = *reinterpret_cast<const int4*>(ei + b);
            int4 s1 = *reinterpret_cast<const int4*>(ei + b + 4);
            int4 d0 = *reinterpret_cast<const int4*>(ei + E_ + b);
            int4 d1 = *reinterpret_cast<const int4*>(ei + E_ + b + 4);
            sorted_src[atomicAdd(&cursor[d0.x], 1)] = s0.x;
            sorted_src[atomicAdd(&cursor[d0.y], 1)] = s0.y;
            sorted_src[atomicAdd(&cursor[d0.z], 1)] = s0.z;
            sorted_src[atomicAdd(&cursor[d0.w], 1)] = s0.w;
            sorted_src[atomicAdd(&cursor[d1.x], 1)] = s1.x;
            sorted_src[atomicAdd(&cursor[d1.y], 1)] = s1.y;
            sorted_src[atomicAdd(&cursor[d1.z], 1)] = s1.z;
            sorted_src[atomicAdd(&cursor[d1.w], 1)] = s1.w;
        } else {
            for (int j = b; j < E_; ++j)
                sorted_src[atomicAdd(&cursor[ei[E_ + j]], 1)] = ei[j];
        }
        return;
    }

    const int lane = t & 63;
    const int w    = t >> 6;
    const int wm   = w >> 1, wn = w & 1;
    const int row0 = ((int)blockIdx.x - nScat) * 128;

    // ---- stage A once: read fp32 x, convert, swizzled ds_write_b128 ----
    #pragma unroll
    for (int i = 0; i < 8; ++i) {
        int L = i * 256 + t;
        int r = L >> 4, ck = L & 15;
        int gr = min(row0 + r, n - 1);
        const float* gp = x + (size_t)gr * 128 + ck * 8;
        f32x4 lo = *reinterpret_cast<const f32x4*>(gp);
        f32x4 hi = *reinterpret_cast<const f32x4*>(gp + 4);
        uint4 o;
        o.x = (uint)f2bf(lo[0]) | ((uint)f2bf(lo[1]) << 16);
        o.y = (uint)f2bf(lo[2]) | ((uint)f2bf(lo[3]) << 16);
        o.z = (uint)f2bf(hi[0]) | ((uint)f2bf(hi[1]) << 16);
        o.w = (uint)f2bf(hi[2]) | ((uint)f2bf(hi[3]) << 16);
        *reinterpret_cast<uint4*>(smA + (size_t)r * 128 + ((ck ^ (r & 7)) << 3)) = o;
    }

    for (int ct = 0; ct < 4; ++ct) {
        __syncthreads();
        #pragma unroll
        for (int i = 0; i < 8; ++i) {
            int L = i * 256 + t;
            int r = L >> 4, ck = L & 15;
            const ushort* gpB = WcatT + (size_t)(ct * 128 + r) * 128 + ((ck ^ (r & 7)) << 3);
            __builtin_amdgcn_global_load_lds((const AS1 void*)gpB,
                (AS3 void*)(smB + (size_t)(i * 256 + (t & 192)) * 8), 16, 0, 0);
        }
        __syncthreads();

        f32x4 acc[4][4];
        #pragma unroll
        for (int i = 0; i < 4; ++i)
            #pragma unroll
            for (int j = 0; j < 4; ++j) acc[i][j] = (f32x4)(0.f);

        #pragma unroll
        for (int kb = 0; kb < 4; ++kb) {
            bf16x8 a[4], b[4];
            #pragma unroll
            for (int rm = 0; rm < 4; ++rm) {
                int r  = wm * 64 + rm * 16 + (lane & 15);
                int ck = (kb * 4 + (lane >> 4)) ^ (r & 7);
                a[rm] = *reinterpret_cast<const bf16x8*>(smA + (size_t)r * 128 + ck * 8);
            }
            #pragma unroll
            for (int cn = 0; cn < 4; ++cn) {
                int r  = wn * 64 + cn * 16 + (lane & 15);
                int ck = (kb * 4 + (lane >> 4)) ^ (r & 7);
                b[cn] = *reinterpret_cast<const bf16x8*>(smB + (size_t)r * 128 + ck * 8);
            }
            #pragma unroll
            for (int rm = 0; rm < 4; ++rm)
                #pragma unroll
                for (int cn = 0; cn < 4; ++cn)
                    acc[rm][cn] = __builtin_amdgcn_mfma_f32_16x16x32_bf16(
                        a[rm], b[cn], acc[rm][cn], 0, 0, 0);
        }

        __syncthreads();
        #pragma unroll
        for (int cn = 0; cn < 4; ++cn) {
            int lc = wn * 64 + cn * 16 + (lane & 15);
            float bias = bcat[ct * 128 + lc];
            #pragma unroll
            for (int rm = 0; rm < 4; ++rm) {
                int R = wm * 64 + rm * 16 + (lane >> 4) * 4;
                #pragma unroll
                for (int rg = 0; rg < 4; ++rg) {
                    int r = R + rg;
                    int addr = r * 128 + ((((lc >> 3) ^ (r & 7)) << 3) | (lc & 7));
                    smB[addr] = f2bf(acc[rm][cn][rg] + bias);
                }
            }
        }
        __syncthreads();
        #pragma unroll
        for (int i = 0; i < 8; ++i) {
            int L = i * 256 + t;
            int r = L >> 4, c16 = L & 15;
            int gr = row0 + r;
            if (gr < n) {
                uint4 o = *reinterpret_cast<const uint4*>(
                    smB + (size_t)r * 128 + ((c16 ^ (r & 7)) << 3));
                *reinterpret_cast<uint4*>(yb + (size_t)gr * 512 + ct * 128 + c16 * 8) = o;
            }
        }
    }
}

// ---------------------------------------------------------------------------
// node_agg: wave per dst node. Lane = (edge-slot g=lane>>4, channel-slot
// il=lane&15, 8 channels each). 4 edges in flight per wave, 3-shfl reduce.
// ---------------------------------------------------------------------------
static __device__ __forceinline__ float dotp(const float q[8], uint4 A, uint4 B) {
    return q[0]*bl(A.x) + q[1]*bh(A.x) + q[2]*bl(A.z) + q[3]*bh(A.z)
         + q[4]*bl(B.x) + q[5]*bh(B.x) + q[6]*bl(B.z) + q[7]*bh(B.z);
}
static __device__ __forceinline__ void accum(float (&acc)[8], float& den,
                                             float a, uint4 A, uint4 B) {
    den += a;
    acc[0] += a*bl(A.y); acc[1] += a*bh(A.y); acc[2] += a*bl(A.w); acc[3] += a*bh(A.w);
    acc[4] += a*bl(B.y); acc[5] += a*bh(B.y); acc[6] += a*bl(B.w); acc[7] += a*bh(B.w);
}

__global__ __launch_bounds__(256) void node_agg(
    const uint* __restrict__ yb32, const int* __restrict__ offs,
    const int* __restrict__ count, const int* __restrict__ sorted_src,
    float* __restrict__ out, int n)
{
    const int node = blockIdx.x * 4 + (threadIdx.x >> 6);
    const int lane = threadIdx.x & 63;
    if (node >= n) return;
    const int g  = lane >> 4;       // edge slot 0..3
    const int il = lane & 15;       // channel slot: channels 8il..8il+7

    const uint* row = yb32 + (size_t)node * 256;  // q:0..63 | kv:64..191 | skip:192..255
    const uint4 qv = *reinterpret_cast<const uint4*>(row + 4 * il);
    float q[8] = { bl(qv.x)*0.125f, bh(qv.x)*0.125f, bl(qv.y)*0.125f, bh(qv.y)*0.125f,
                   bl(qv.z)*0.125f, bh(qv.z)*0.125f, bl(qv.w)*0.125f, bh(qv.w)*0.125f };

    const int deg = count[node];
    const int* sp = sorted_src + offs[node];

    float acc[8] = {0.f,0.f,0.f,0.f,0.f,0.f,0.f,0.f};
    float den = 0.f;

    int e = 0;
    for (; e + 8 <= deg; e += 8) {            // two full quads, no masking
        const int sA = sp[e + g], sB = sp[e + 4 + g];
        const uint* pa = yb32 + (size_t)sA * 256 + 64 + 8 * il;
        const uint* pb = yb32 + (size_t)sB * 256 + 64 + 8 * il;
        uint4 Aa = *reinterpret_cast<const uint4*>(pa);
        uint4 Ba = *reinterpret_cast<const uint4*>(pa + 4);
        uint4 Ab = *reinterpret_cast<const uint4*>(pb);
        uint4 Bb = *reinterpret_cast<const uint4*>(pb + 4);
        float p1 = dotp(q, Aa, Ba);
        float p2 = dotp(q, Ab, Bb);
        p1 += __shfl_xor(p1, 1, 64);  p2 += __shfl_xor(p2, 1, 64);
        p1 += __shfl_xor(p1, 2, 64);  p2 += __shfl_xor(p2, 2, 64);
        p1 += __shfl_xor(p1, 4, 64);  p2 += __shfl_xor(p2, 4, 64);
        float a1 = __expf(p1), a2 = __expf(p2);
        accum(acc, den, a1, Aa, Ba);
        accum(acc, den, a2, Ab, Bb);
    }
    for (; e < deg; e += 4) {                 // masked tail quads
        const int idx = e + g;
        const bool act = idx < deg;
        const int s = sp[act ? idx : deg - 1];
        const uint* pa = yb32 + (size_t)s * 256 + 64 + 8 * il;
        uint4 A = *reinterpret_cast<const uint4*>(pa);
        uint4 B = *reinterpret_cast<const uint4*>(pa + 4);
        float p = dotp(q, A, B);
        p += __shfl_xor(p, 1, 64);
        p += __shfl_xor(p, 2, 64);
        p += __shfl_xor(p, 4, 64);
        float a = act ? __expf(p) : 0.f;
        accum(acc, den, a, A, B);
    }

    // combine the 4 edge-slots (lanes l, l^16, l^32, l^48)
    #pragma unroll
    for (int j = 0; j < 8; ++j) {
        acc[j] += __shfl_xor(acc[j], 16, 64);
        acc[j] += __shfl_xor(acc[j], 32, 64);
    }
    den += __shfl_xor(den, 16, 64);
    den += __shfl_xor(den, 32, 64);

    if (lane < 16) {                          // il = lane, head = il>>3
        const float inv = 1.f / fmaxf(den, 1e-16f);
        const uint4 sv = *reinterpret_cast<const uint4*>(row + 192 + 4 * il);
        f32x4 o0, o1;
        o0[0] = acc[0]*inv + bl(sv.x);  o0[1] = acc[1]*inv + bh(sv.x);
        o0[2] = acc[2]*inv + bl(sv.y);  o0[3] = acc[3]*inv + bh(sv.y);
        o1[0] = acc[4]*inv + bl(sv.z);  o1[1] = acc[5]*inv + bh(sv.z);
        o1[2] = acc[6]*inv + bl(sv.w);  o1[3] = acc[7]*inv + bh(sv.w);
        float* op = out + (size_t)node * 128 + 8 * il;
        *reinterpret_cast<f32x4*>(op)     = o0;
        *reinterpret_cast<f32x4*>(op + 4) = o1;
    }
}

extern "C" void kernel_launch(void* const* d_in, const int* in_sizes, int n_in,
                              void* d_out, int out_size, void* d_ws, size_t ws_size,
                              hipStream_t stream) {
    const float* x  = (const float*)d_in[0];
    const int*   ei = (const int*)d_in[1];
    const float* Wq = (const float*)d_in[2];
    const float* bq = (const float*)d_in[3];
    const float* Wk = (const float*)d_in[4];
    const float* bk = (const float*)d_in[5];
    const float* Wv = (const float*)d_in[6];
    const float* bv = (const float*)d_in[7];
    const float* Ws = (const float*)d_in[8];
    const float* bs = (const float*)d_in[9];

    const int N = in_sizes[0] / 128;
    const int E = in_sizes[1] / 2;

    ushort* yb    = (ushort*)d_ws;                       // [N][512] bf16
    ushort* WcatT = yb + (size_t)N * 512;                // [512][128] bf16
    float*  bcat  = (float*)(WcatT + 512 * 128);         // [512]
    int* count      = (int*)(bcat + 512);                // [N]
    int* gcount     = count + N;                         // [1]
    int* offs       = gcount + 1;                        // [N]
    int* cursor     = offs + N;                          // [N]
    int* sorted_src = cursor + N;                        // [E]
    float* out      = (float*)d_out;

    hipMemsetAsync(count, 0, (size_t)(N + 1) * sizeof(int), stream);  // count+gcount

    const int histBlocks = (E / 4 + 255) / 256;
    setup_kernel<<<256 + histBlocks, 256, 0, stream>>>(
        Wq, bq, Wk, bk, Wv, bv, Ws, bs, WcatT, bcat, ei, count, E);

    bucket_assign<<<(N + 255) / 256, 256, 0, stream>>>(count, offs, cursor, gcount, N);

    const int nScat = (E + 2047) / 2048;
    const int nMfma = (N + 127) / 128;
    fused_mid<<<nScat + nMfma, 256, 0, stream>>>(
        x, WcatT, bcat, yb, N, ei, cursor, sorted_src, E, nScat);

    node_agg<<<(N + 3) / 4, 256, 0, stream>>>((const uint*)yb, offs, count, sorted_src, out, N);
}